// Round 12
// baseline (4976.125 us; speedup 1.0000x reference)
//
#include <hip/hip_runtime.h>

// Problem constants
#define NB 8
#define NT 1024
#define ND 768     // = 12*64
#define NH 12
#define NU 64
#define BT (NB*NT)   // 8192
#define SCALE32 ((float)0.03608439182435161)  // fp32(768^-0.5)
#define EPS32 1e-7f

// ---------------------------------------------------------------------------
// numpy baseline-SIMD (SSE2, no FMA) einsum dot over 64 contiguous elements:
// 4 accumulators stride-4, separate mul/add (rounded each), reduce
// (r0+r2)+(r1+r3). __f*_rn blocks hipcc contraction. BITWISE-IDENTICAL.
// ---------------------------------------------------------------------------
__device__ __forceinline__ float dot64_np(const float* a, const float* b)
{
    float r[4];
#pragma unroll
    for (int j = 0; j < 4; j++) r[j] = __fmul_rn(a[j], b[j]);
#pragma unroll
    for (int i = 1; i < 16; i++)
#pragma unroll
        for (int j = 0; j < 4; j++)
            r[j] = __fadd_rn(r[j], __fmul_rn(a[i * 4 + j], b[i * 4 + j]));
    return __fadd_rn(__fadd_rn(r[0], r[2]), __fadd_rn(r[1], r[3]));
}

// ---------------------------------------------------------------------------
// Mask decode with byte/int32 layout sniff (mask is all-ones in practice).
// ---------------------------------------------------------------------------
__global__ __launch_bounds__(256) void mask_k(
    const unsigned char* __restrict__ mb, float* __restrict__ mf)
{
    __shared__ int cntOff, cntAll;
    if (threadIdx.x == 0) { cntOff = 0; cntAll = 0; }
    __syncthreads();
    int lo = 0, la = 0;
    for (int i = threadIdx.x; i < BT; i += 256)
        if (mb[i] != 0) { la++; if ((i & 3) != 0) lo++; }
    atomicAdd(&cntOff, lo);
    atomicAdd(&cntAll, la);
    __syncthreads();
    const bool int32mode = (cntOff == 0) && (cntAll != 0);
    if (int32mode) {
        const int* mi = (const int*)mb;
        for (int i = threadIdx.x; i < BT; i += 256)
            mf[i] = (mi[i] != 0) ? 1.f : 0.f;
    } else {
        for (int i = threadIdx.x; i < BT; i += 256)
            mf[i] = (mb[i] != 0) ? 1.f : 0.f;
    }
}

// ---------------------------------------------------------------------------
// OpenBLAS-mimic sgemm: 128x64 tile, 8x4 micro (R9 champion). kc=384 panel
// split preserved bitwise. grid (64,12). Unchanged.
// ---------------------------------------------------------------------------
__global__ __launch_bounds__(256) void gemmseq(
    const float* __restrict__ A, const float* __restrict__ W,
    const float* __restrict__ R, float* __restrict__ C)
{
    __shared__ float sA[64][132];  // [k][m], transposed, 128 m + 4 pad
    __shared__ float sB[64][68];   // [k][n]

    const int t = threadIdx.x;
    const int mbase = blockIdx.x * 128;
    const int nbase = blockIdx.y * 64;
    const int m0 = (t >> 4) * 8;
    const int n0 = (t & 15) * 4;

    float acc[8][4], accA[8][4];
#pragma unroll
    for (int i = 0; i < 8; i++)
#pragma unroll
        for (int j = 0; j < 4; j++) { acc[i][j] = 0.f; accA[i][j] = 0.f; }

    for (int k0 = 0; k0 < 768; k0 += 64) {
        __syncthreads();
#pragma unroll
        for (int i = 0; i < 8; i++) {           // A tile: 128 rows x 64 k
            const int idx = t + i * 256;        // 0..2047
            const int ar = idx >> 4;            // 0..127
            const int ak4 = (idx & 15) * 4;     // 0..60
            const float4 a4 = *(const float4*)&A[(size_t)(mbase + ar) * 768 + k0 + ak4];
            sA[ak4 + 0][ar] = a4.x;
            sA[ak4 + 1][ar] = a4.y;
            sA[ak4 + 2][ar] = a4.z;
            sA[ak4 + 3][ar] = a4.w;
        }
#pragma unroll
        for (int i = 0; i < 4; i++) {           // B tile: 64 rows x 64 n
            const int idx = t + i * 256;        // 0..1023
            const int br = idx >> 4;            // 0..63
            const int bk4 = (idx & 15) * 4;     // 0..60
            *(float4*)&sB[br][bk4] =
                *(const float4*)&W[(size_t)(k0 + br) * 768 + nbase + bk4];
        }
        __syncthreads();

        for (int kk = 0; kk < 64; kk++) {
            float av[8], bv[4];
            *(float4*)&av[0] = *(const float4*)&sA[kk][m0];
            *(float4*)&av[4] = *(const float4*)&sA[kk][m0 + 4];
            *(float4*)&bv[0] = *(const float4*)&sB[kk][n0];
#pragma unroll
            for (int i = 0; i < 8; i++)
#pragma unroll
                for (int j = 0; j < 4; j++)
                    acc[i][j] = fmaf(av[i], bv[j], acc[i][j]);
        }

        if (k0 + 64 == 384) {   // end of first kc panel (OpenBLAS kc=384)
#pragma unroll
            for (int i = 0; i < 8; i++)
#pragma unroll
                for (int j = 0; j < 4; j++) {
                    accA[i][j] = acc[i][j];
                    acc[i][j] = 0.f;
                }
        }
    }

#pragma unroll
    for (int i = 0; i < 8; i++)
#pragma unroll
        for (int j = 0; j < 4; j++) {
            const size_t idx = (size_t)(mbase + m0 + i) * 768 + nbase + n0 + j;
            float o = __fadd_rn(accA[i][j], acc[i][j]);  // C = panel0 + panel1
            if (R) o = __fadd_rn(o, R[idx]);             // np: out = tmp + x
            C[idx] = o;
        }
}

// ---------------------------------------------------------------------------
// Denominator, j-parity split: TWO threads per row (p = tid&1). The 8 b8[j]
// chains are independent; thread p owns j in {4p..4p+3} and visits ONLY its
// 512 s-values (sg = c*128 + k*8 + 4p + i, k ascending = exact serial chain
// per j). Bi[c] = fadd(L,R): p0 computes L=(b0+b1)+(b2+b3), p1 computes R;
// shfl_xor(.,1) exchanges; both lanes form fadd(L,R) — reference tree,
// bitwise. Work per thread HALVED, waves doubled (12/CU). q stays champion
// qr[64]; K per-lane (2 addresses/wave -> 2-segment VMEM loads).
// 64 rows/block, grid 1536, XCD-swizzled (cpx=192). Write at p==0.
// ---------------------------------------------------------------------------
__global__ __launch_bounds__(128) void denom_np(
    const float* __restrict__ Q, const float* __restrict__ K,
    const float* __restrict__ MF, float* __restrict__ D)
{
    const int bid = blockIdx.x;
    const int lb  = (bid & 7) * 192 + (bid >> 3);    // XCD-grouped logical id
    const int tid = threadIdx.x;
    const int rowg = lb * 64 + (tid >> 1);           // 0..98303
    const int p   = tid & 1;
    const int bh  = rowg >> 10;
    const int row = rowg & 1023;
    const int b = bh / NH, h = bh % NH;

    const float mq = MF[b * NT + row];

    float qr[64];
    const float4* qp = (const float4*)&Q[((size_t)(b * NT + row)) * ND + h * 64];
#pragma unroll
    for (int i = 0; i < 16; i++) *(float4*)&qr[i * 4] = qp[i];

    const float* Kb  = &K[((size_t)(b * NT)) * ND + h * 64];
    const float* MFb = &MF[b * NT];
    const int j0 = 4 * p;

    float Bi[8];
    for (int c = 0; c < 8; c++) {
        float b8[4];
        for (int k = 0; k < 16; k++) {
#pragma unroll
            for (int i = 0; i < 4; i++) {
                const int sg = c * 128 + k * 8 + j0 + i;
                const float dt = dot64_np(qr, Kb + (size_t)sg * ND);
                float sc = __fmul_rn(dt, SCALE32);
                sc = __fmul_rn(sc, MFb[sg]);
                sc = __fmul_rn(sc, mq);
                if (k == 0) b8[i] = sc;
                else        b8[i] = __fadd_rn(b8[i], sc);
            }
        }
        const float half = __fadd_rn(__fadd_rn(b8[0], b8[1]), __fadd_rn(b8[2], b8[3]));
        const float other = __shfl_xor(half, 1, 64);
        const float L = (p == 0) ? half : other;
        const float R = (p == 0) ? other : half;
        Bi[c] = __fadd_rn(L, R);
    }

    if (p == 0)
        D[(size_t)bh * NT + row] = __fadd_rn(
            __fadd_rn(__fadd_rn(Bi[0], Bi[1]), __fadd_rn(Bi[2], Bi[3])),
            __fadd_rn(__fadd_rn(Bi[4], Bi[5]), __fadd_rn(Bi[6], Bi[7])));
}

// ---------------------------------------------------------------------------
// Attention out, s-parity split: TWO threads per row (p = tid&1). Thread p
// computes the dot/score/divide ONLY for s = 2*step+p (dot chain is the
// exact serial sequence — identical bits whichever lane runs it; fdiv count
// per row unchanged, split across the pair). shfl_xor(.,1) exchanges the
// two p-values; each thread applies BOTH, even-s first, to its own 32
// contiguous o-channels [32p, 32p+32) — every o[j] chain sees s ascending
// 0..1023 exactly as the reference. Per-thread: dots, fdivs, axpy, and
// q-scratch traffic all halved; waves doubled (12/CU).
// 64 rows/block, grid 1536, XCD-swizzled. Self-aliased QA (q read before
// loop; each output dword written by exactly one owner).
// ---------------------------------------------------------------------------
__global__ __launch_bounds__(128) void attn_np(
    const float* __restrict__ K, const float* __restrict__ V,
    const float* __restrict__ D, const float* __restrict__ MF,
    float* __restrict__ QA)   // in: Q, out: A (self-aliased per row)
{
    const int bid = blockIdx.x;
    const int lb  = (bid & 7) * 192 + (bid >> 3);    // XCD-grouped logical id
    const int tid = threadIdx.x;
    const int rowg = lb * 64 + (tid >> 1);
    const int p   = tid & 1;
    const int bh  = rowg >> 10;
    const int row = rowg & 1023;
    const int b = bh / NH, h = bh % NH;

    const float mq = MF[b * NT + row];
    const float De = __fadd_rn(D[(size_t)bh * NT + row], EPS32);  // np: sum+eps

    float qr[64];
    const float4* qp = (const float4*)&QA[((size_t)(b * NT + row)) * ND + h * 64];
#pragma unroll
    for (int i = 0; i < 16; i++) *(float4*)&qr[i * 4] = qp[i];

    float o[32];
#pragma unroll
    for (int j = 0; j < 32; j++) o[j] = 0.f;

    const float* Kb   = &K[((size_t)(b * NT)) * ND + h * 64];
    const float* Vb32 = &V[((size_t)(b * NT)) * ND + h * 64 + 32 * p];
    const float* MFb  = &MF[b * NT];

    for (int step = 0; step < 512; step++) {
        const int sme = 2 * step + p;                 // my parity's s
        const float dt = dot64_np(qr, Kb + (size_t)sme * ND);
        float sc = __fmul_rn(dt, SCALE32);
        sc = __fmul_rn(sc, MFb[sme]);
        sc = __fmul_rn(sc, mq);
        const float pv = __fdiv_rn(sc, De);
        const float pw = __shfl_xor(pv, 1, 64);       // partner parity's p
        const float pe = (p == 0) ? pv : pw;          // p for s = 2*step
        const float po = (p == 0) ? pw : pv;          // p for s = 2*step+1
        const float* vpe = Vb32 + (size_t)(2 * step) * ND;
        const float* vpo = vpe + ND;
#pragma unroll
        for (int j = 0; j < 32; j++)
            o[j] = __fadd_rn(o[j], __fmul_rn(pe, vpe[j]));   // s even
#pragma unroll
        for (int j = 0; j < 32; j++)
            o[j] = __fadd_rn(o[j], __fmul_rn(po, vpo[j]));   // s odd
    }

    float4* op = (float4*)&QA[((size_t)(b * NT + row)) * ND + h * 64 + 32 * p];
#pragma unroll
    for (int i = 0; i < 8; i++) op[i] = *(float4*)&o[i * 4];
}

// ---------------------------------------------------------------------------
// Row norm, numpy-faithful pairwise mean via ONE WAVE per row (unchanged).
// ---------------------------------------------------------------------------
__global__ __launch_bounds__(256) void rownorm_np(
    float* __restrict__ Y, const float* __restrict__ gamma,
    const float* __restrict__ beta)
{
    const int wave = threadIdx.x >> 6, lane = threadIdx.x & 63;
    const int row = blockIdx.x * 4 + wave;
    float* yr = Y + (size_t)row * ND;
    const int c = lane >> 3, j = lane & 7;

    const float* a = yr + c * 96;
    float r = a[j];
#pragma unroll
    for (int i = 1; i < 12; i++) r = __fadd_rn(r, a[i * 8 + j]);

    r = __fadd_rn(r, __shfl_xor(r, 1, 64));
    r = __fadd_rn(r, __shfl_xor(r, 2, 64));
    r = __fadd_rn(r, __shfl_xor(r, 4, 64));
    r = __fadd_rn(r, __shfl_xor(r, 8, 64));
    r = __fadd_rn(r, __shfl_xor(r, 16, 64));
    r = __fadd_rn(r, __shfl_xor(r, 32, 64));

    const float m = __fdiv_rn(r, 768.0f);
    const float mpe = __fadd_rn(m, EPS32);

#pragma unroll
    for (int i = 0; i < 12; i++) {
        const int idx = i * 64 + lane;
        const float v = yr[idx];
        float o = __fsub_rn(v, m);
        o = __fmul_rn(gamma[idx], o);
        o = __fdiv_rn(o, mpe);
        o = __fadd_rn(o, beta[idx]);
        yr[idx] = o;
    }
}

// ---------------------------------------------------------------------------
extern "C" void kernel_launch(void* const* d_in, const int* in_sizes, int n_in,
                              void* d_out, int out_size, void* d_ws, size_t ws_size,
                              hipStream_t stream)
{
    (void)in_sizes; (void)n_in; (void)out_size; (void)ws_size;
    const float* x     = (const float*)d_in[0];
    const unsigned char* maskb = (const unsigned char*)d_in[1];
    const float* wq    = (const float*)d_in[2];
    const float* wk    = (const float*)d_in[3];
    const float* wv    = (const float*)d_in[4];
    const float* wf    = (const float*)d_in[5];
    const float* gamma = (const float*)d_in[6];
    const float* beta  = (const float*)d_in[7];

    float* ws = (float*)d_ws;
    float* MF = ws;                             // 8192
    float* D  = MF + BT;                        // 96*1024
    float* Q  = D + (size_t)96 * NT;            // 8192*768 (becomes A)
    float* K  = Q + (size_t)BT * ND;            // 8192*768
    float* V  = K + (size_t)BT * ND;            // 8192*768
    float* Y  = (float*)d_out;                  // total ws: 75.9 MB

    mask_k<<<1, 256, 0, stream>>>(maskb, MF);
    gemmseq<<<dim3(64, 12), 256, 0, stream>>>(x, wq, nullptr, Q);
    gemmseq<<<dim3(64, 12), 256, 0, stream>>>(x, wk, nullptr, K);
    gemmseq<<<dim3(64, 12), 256, 0, stream>>>(x, wv, nullptr, V);
    denom_np<<<1536, 128, 0, stream>>>(Q, K, MF, D);
    attn_np<<<1536, 128, 0, stream>>>(K, V, D, MF, Q);  // Q -> A
    gemmseq<<<dim3(64, 12), 256, 0, stream>>>(Q, wf, x, Y);
    rownorm_np<<<2048, 256, 0, stream>>>(Y, gamma, beta);
}

// Round 13
// 1751.714 us; speedup vs baseline: 2.8407x; 2.8407x over previous
//
#include <hip/hip_runtime.h>

// Problem constants
#define NB 8
#define NT 1024
#define ND 768     // = 12*64
#define NH 12
#define NU 64
#define BT (NB*NT)   // 8192
#define SCALE32 ((float)0.03608439182435161)  // fp32(768^-0.5)
#define EPS32 1e-7f

// ---------------------------------------------------------------------------
// numpy baseline-SIMD (SSE2, no FMA) einsum dot over 64 contiguous elements:
// 4 accumulators stride-4, separate mul/add (rounded each), reduce
// (r0+r2)+(r1+r3). __f*_rn blocks hipcc contraction. BITWISE-IDENTICAL.
// ---------------------------------------------------------------------------
__device__ __forceinline__ float dot64_np(const float* a, const float* b)
{
    float r[4];
#pragma unroll
    for (int j = 0; j < 4; j++) r[j] = __fmul_rn(a[j], b[j]);
#pragma unroll
    for (int i = 1; i < 16; i++)
#pragma unroll
        for (int j = 0; j < 4; j++)
            r[j] = __fadd_rn(r[j], __fmul_rn(a[i * 4 + j], b[i * 4 + j]));
    return __fadd_rn(__fadd_rn(r[0], r[2]), __fadd_rn(r[1], r[3]));
}

// ---------------------------------------------------------------------------
// Mask decode with byte/int32 layout sniff (mask is all-ones in practice).
// ---------------------------------------------------------------------------
__global__ __launch_bounds__(256) void mask_k(
    const unsigned char* __restrict__ mb, float* __restrict__ mf)
{
    __shared__ int cntOff, cntAll;
    if (threadIdx.x == 0) { cntOff = 0; cntAll = 0; }
    __syncthreads();
    int lo = 0, la = 0;
    for (int i = threadIdx.x; i < BT; i += 256)
        if (mb[i] != 0) { la++; if ((i & 3) != 0) lo++; }
    atomicAdd(&cntOff, lo);
    atomicAdd(&cntAll, la);
    __syncthreads();
    const bool int32mode = (cntOff == 0) && (cntAll != 0);
    if (int32mode) {
        const int* mi = (const int*)mb;
        for (int i = threadIdx.x; i < BT; i += 256)
            mf[i] = (mi[i] != 0) ? 1.f : 0.f;
    } else {
        for (int i = threadIdx.x; i < BT; i += 256)
            mf[i] = (mb[i] != 0) ? 1.f : 0.f;
    }
}

// ---------------------------------------------------------------------------
// OpenBLAS-mimic sgemm: 128x64 tile, 8x4 micro (R9 champion). kc=384 panel
// split preserved bitwise. grid (64,12). Unchanged.
// ---------------------------------------------------------------------------
__global__ __launch_bounds__(256) void gemmseq(
    const float* __restrict__ A, const float* __restrict__ W,
    const float* __restrict__ R, float* __restrict__ C)
{
    __shared__ float sA[64][132];  // [k][m], transposed, 128 m + 4 pad
    __shared__ float sB[64][68];   // [k][n]

    const int t = threadIdx.x;
    const int mbase = blockIdx.x * 128;
    const int nbase = blockIdx.y * 64;
    const int m0 = (t >> 4) * 8;
    const int n0 = (t & 15) * 4;

    float acc[8][4], accA[8][4];
#pragma unroll
    for (int i = 0; i < 8; i++)
#pragma unroll
        for (int j = 0; j < 4; j++) { acc[i][j] = 0.f; accA[i][j] = 0.f; }

    for (int k0 = 0; k0 < 768; k0 += 64) {
        __syncthreads();
#pragma unroll
        for (int i = 0; i < 8; i++) {           // A tile: 128 rows x 64 k
            const int idx = t + i * 256;        // 0..2047
            const int ar = idx >> 4;            // 0..127
            const int ak4 = (idx & 15) * 4;     // 0..60
            const float4 a4 = *(const float4*)&A[(size_t)(mbase + ar) * 768 + k0 + ak4];
            sA[ak4 + 0][ar] = a4.x;
            sA[ak4 + 1][ar] = a4.y;
            sA[ak4 + 2][ar] = a4.z;
            sA[ak4 + 3][ar] = a4.w;
        }
#pragma unroll
        for (int i = 0; i < 4; i++) {           // B tile: 64 rows x 64 n
            const int idx = t + i * 256;        // 0..1023
            const int br = idx >> 4;            // 0..63
            const int bk4 = (idx & 15) * 4;     // 0..60
            *(float4*)&sB[br][bk4] =
                *(const float4*)&W[(size_t)(k0 + br) * 768 + nbase + bk4];
        }
        __syncthreads();

        for (int kk = 0; kk < 64; kk++) {
            float av[8], bv[4];
            *(float4*)&av[0] = *(const float4*)&sA[kk][m0];
            *(float4*)&av[4] = *(const float4*)&sA[kk][m0 + 4];
            *(float4*)&bv[0] = *(const float4*)&sB[kk][n0];
#pragma unroll
            for (int i = 0; i < 8; i++)
#pragma unroll
                for (int j = 0; j < 4; j++)
                    acc[i][j] = fmaf(av[i], bv[j], acc[i][j]);
        }

        if (k0 + 64 == 384) {   // end of first kc panel (OpenBLAS kc=384)
#pragma unroll
            for (int i = 0; i < 8; i++)
#pragma unroll
                for (int j = 0; j < 4; j++) {
                    accA[i][j] = acc[i][j];
                    acc[i][j] = 0.f;
                }
        }
    }

#pragma unroll
    for (int i = 0; i < 8; i++)
#pragma unroll
        for (int j = 0; j < 4; j++) {
            const size_t idx = (size_t)(mbase + m0 + i) * 768 + nbase + n0 + j;
            float o = __fadd_rn(accA[i][j], acc[i][j]);  // C = panel0 + panel1
            if (R) o = __fadd_rn(o, R[idx]);             // np: out = tmp + x
            C[idx] = o;
        }
}

// ---------------------------------------------------------------------------
// FUSED denominator + attention. One THREAD per row (champion structure,
// wave-uniform K/V s_load batches, XCD swizzle).
//
// Pass 1 = exact champion denom: per s, dot (127 VALU) + K SMEM batch; the
// masked/scaled score sc is ADDITIONALLY stored to a private per-thread
// scratch array sarr[1024] (runtime-indexed -> scratch by design, on the
// otherwise-idle VMEM path). b8/Bi pairwise trees unchanged -> De computed
// LOCALLY (register->scratch->register is bit-lossless; the global D
// round-trip of the split version carried identical bits).
//
// Pass 2: axpy-only loop: sc reloaded from scratch (1 VMEM b32), one fdiv,
// V row = a SINGLE SMEM batch-drain per iteration (vs K+V = 2 in the
// unfused attn), no dot, no q. Net per row: 2048 SMEM drains vs 3072, and
// the 1024-dot recompute eliminated.
//
// Bitwise: every arithmetic op identical to the champion pair; only the
// transport of sc changed (global S -> private scratch).
// Self-aliased QA: q read in pass 1, A written after pass 2, own thread only.
// grid 768 x 128.
// ---------------------------------------------------------------------------
__global__ __launch_bounds__(128) void attn_fused(
    const float* __restrict__ K, const float* __restrict__ V,
    const float* __restrict__ MF, float* __restrict__ QA)
{
    const int bid = blockIdx.x;
    const int lb  = (bid & 7) * 96 + (bid >> 3);     // XCD-grouped logical id
    const int gid = lb * 128 + threadIdx.x;          // 0..98303
    const int bh = gid >> 10;                        // uniform per block
    const int row = gid & 1023;
    const int b = bh / NH, h = bh % NH;
    const int bh_u = __builtin_amdgcn_readfirstlane(bh);
    const int b_u = bh_u / NH, h_u = bh_u % NH;

    const float mq = MF[b * NT + row];

    float qr[64];
    const float4* qp = (const float4*)&QA[((size_t)(b * NT + row)) * ND + h * 64];
#pragma unroll
    for (int i = 0; i < 16; i++) *(float4*)&qr[i * 4] = qp[i];

    const float* Kb = &K[((size_t)(b_u * NT)) * ND + h_u * 64];
    const float* Vb = &V[((size_t)(b_u * NT)) * ND + h_u * 64];
    const float* MFb = &MF[b_u * NT];

    float sarr[NT];   // private scratch: the 1024 masked scores of this row

    // ---- Pass 1: scores + denominator (champion denom arithmetic) ----
    float Bi[8];
    for (int c = 0; c < 8; c++) {
        float b8[8];
        for (int s = 0; s < 128; s++) {
            const int sg = c * 128 + s;
            const float dt = dot64_np(qr, Kb + (size_t)sg * ND); // uniform k
            float sc = __fmul_rn(dt, SCALE32);
            sc = __fmul_rn(sc, MFb[sg]);
            sc = __fmul_rn(sc, mq);
            sarr[sg] = sc;
            const int j = s & 7;
            if (s < 8) b8[j] = sc;
            else       b8[j] = __fadd_rn(b8[j], sc);
        }
        Bi[c] = __fadd_rn(__fadd_rn(__fadd_rn(b8[0], b8[1]), __fadd_rn(b8[2], b8[3])),
                          __fadd_rn(__fadd_rn(b8[4], b8[5]), __fadd_rn(b8[6], b8[7])));
    }
    const float Drow = __fadd_rn(
        __fadd_rn(__fadd_rn(Bi[0], Bi[1]), __fadd_rn(Bi[2], Bi[3])),
        __fadd_rn(__fadd_rn(Bi[4], Bi[5]), __fadd_rn(Bi[6], Bi[7])));
    const float De = __fadd_rn(Drow, EPS32);         // np: sum + eps

    // ---- Pass 2: normalize + weighted V accumulation ----
    float o[64];
#pragma unroll
    for (int j = 0; j < 64; j++) o[j] = 0.f;

    for (int s = 0; s < NT; s++) {
        const float p = __fdiv_rn(sarr[s], De);      // same bits as unfused
        const float* vp = Vb + (size_t)s * ND;       // uniform v, 1 drain
#pragma unroll
        for (int j = 0; j < 64; j++)
            o[j] = __fadd_rn(o[j], __fmul_rn(p, vp[j]));  // np SSE2 axpy
    }

    float4* op = (float4*)&QA[((size_t)(b * NT + row)) * ND + h * 64];
#pragma unroll
    for (int i = 0; i < 16; i++) op[i] = *(float4*)&o[i * 4];
}

// ---------------------------------------------------------------------------
// Row norm, numpy-faithful pairwise mean via ONE WAVE per row (unchanged).
// ---------------------------------------------------------------------------
__global__ __launch_bounds__(256) void rownorm_np(
    float* __restrict__ Y, const float* __restrict__ gamma,
    const float* __restrict__ beta)
{
    const int wave = threadIdx.x >> 6, lane = threadIdx.x & 63;
    const int row = blockIdx.x * 4 + wave;
    float* yr = Y + (size_t)row * ND;
    const int c = lane >> 3, j = lane & 7;

    const float* a = yr + c * 96;
    float r = a[j];
#pragma unroll
    for (int i = 1; i < 12; i++) r = __fadd_rn(r, a[i * 8 + j]);

    r = __fadd_rn(r, __shfl_xor(r, 1, 64));
    r = __fadd_rn(r, __shfl_xor(r, 2, 64));
    r = __fadd_rn(r, __shfl_xor(r, 4, 64));
    r = __fadd_rn(r, __shfl_xor(r, 8, 64));
    r = __fadd_rn(r, __shfl_xor(r, 16, 64));
    r = __fadd_rn(r, __shfl_xor(r, 32, 64));

    const float m = __fdiv_rn(r, 768.0f);
    const float mpe = __fadd_rn(m, EPS32);

#pragma unroll
    for (int i = 0; i < 12; i++) {
        const int idx = i * 64 + lane;
        const float v = yr[idx];
        float o = __fsub_rn(v, m);
        o = __fmul_rn(gamma[idx], o);
        o = __fdiv_rn(o, mpe);
        o = __fadd_rn(o, beta[idx]);
        yr[idx] = o;
    }
}

// ---------------------------------------------------------------------------
extern "C" void kernel_launch(void* const* d_in, const int* in_sizes, int n_in,
                              void* d_out, int out_size, void* d_ws, size_t ws_size,
                              hipStream_t stream)
{
    (void)in_sizes; (void)n_in; (void)out_size; (void)ws_size;
    const float* x     = (const float*)d_in[0];
    const unsigned char* maskb = (const unsigned char*)d_in[1];
    const float* wq    = (const float*)d_in[2];
    const float* wk    = (const float*)d_in[3];
    const float* wv    = (const float*)d_in[4];
    const float* wf    = (const float*)d_in[5];
    const float* gamma = (const float*)d_in[6];
    const float* beta  = (const float*)d_in[7];

    float* ws = (float*)d_ws;
    float* MF = ws;                             // 8192
    float* Q  = MF + BT;                        // 8192*768 (becomes A)
    float* K  = Q + (size_t)BT * ND;            // 8192*768
    float* V  = K + (size_t)BT * ND;            // 8192*768
    float* Y  = (float*)d_out;                  // total ws: 75.5 MB

    mask_k<<<1, 256, 0, stream>>>(maskb, MF);
    gemmseq<<<dim3(64, 12), 256, 0, stream>>>(x, wq, nullptr, Q);
    gemmseq<<<dim3(64, 12), 256, 0, stream>>>(x, wk, nullptr, K);
    gemmseq<<<dim3(64, 12), 256, 0, stream>>>(x, wv, nullptr, V);
    attn_fused<<<768, 128, 0, stream>>>(K, V, MF, Q);   // Q -> A (D internal)
    gemmseq<<<dim3(64, 12), 256, 0, stream>>>(Q, wf, x, Y);
    rownorm_np<<<2048, 256, 0, stream>>>(Y, gamma, beta);
}

// Round 14
// 1739.725 us; speedup vs baseline: 2.8603x; 1.0069x over previous
//
#include <hip/hip_runtime.h>

// Problem constants
#define NB 8
#define NT 1024
#define ND 768     // = 12*64
#define NH 12
#define NU 64
#define BT (NB*NT)   // 8192
#define SCALE32 ((float)0.03608439182435161)  // fp32(768^-0.5)
#define EPS32 1e-7f

// ---------------------------------------------------------------------------
// numpy SSE2-mimic dot64 over native float4 arrays with COMPILE-TIME-CONSTANT
// indices (fully unrolled): the SROA-promotable formulation. Chain identical
// to the reference dot64_np: r[j] = accumulator for elements j, 4+j, ... ;
// r0<->.x, r1<->.y, r2<->.z, r3<->.w; init at i=0, adds i=1..15 (each
// mul/add individually rounded), reduce (r0+r2)+(r1+r3). BITWISE-IDENTICAL.
// ---------------------------------------------------------------------------
__device__ __forceinline__ float dot64_f4(const float4* qf, const float4* kf)
{
    float r0 = __fmul_rn(qf[0].x, kf[0].x);
    float r1 = __fmul_rn(qf[0].y, kf[0].y);
    float r2 = __fmul_rn(qf[0].z, kf[0].z);
    float r3 = __fmul_rn(qf[0].w, kf[0].w);
#pragma unroll
    for (int i = 1; i < 16; i++) {
        r0 = __fadd_rn(r0, __fmul_rn(qf[i].x, kf[i].x));
        r1 = __fadd_rn(r1, __fmul_rn(qf[i].y, kf[i].y));
        r2 = __fadd_rn(r2, __fmul_rn(qf[i].z, kf[i].z));
        r3 = __fadd_rn(r3, __fmul_rn(qf[i].w, kf[i].w));
    }
    return __fadd_rn(__fadd_rn(r0, r2), __fadd_rn(r1, r3));
}

// ---------------------------------------------------------------------------
// Mask decode with byte/int32 layout sniff (mask is all-ones in practice).
// ---------------------------------------------------------------------------
__global__ __launch_bounds__(256) void mask_k(
    const unsigned char* __restrict__ mb, float* __restrict__ mf)
{
    __shared__ int cntOff, cntAll;
    if (threadIdx.x == 0) { cntOff = 0; cntAll = 0; }
    __syncthreads();
    int lo = 0, la = 0;
    for (int i = threadIdx.x; i < BT; i += 256)
        if (mb[i] != 0) { la++; if ((i & 3) != 0) lo++; }
    atomicAdd(&cntOff, lo);
    atomicAdd(&cntAll, la);
    __syncthreads();
    const bool int32mode = (cntOff == 0) && (cntAll != 0);
    if (int32mode) {
        const int* mi = (const int*)mb;
        for (int i = threadIdx.x; i < BT; i += 256)
            mf[i] = (mi[i] != 0) ? 1.f : 0.f;
    } else {
        for (int i = threadIdx.x; i < BT; i += 256)
            mf[i] = (mb[i] != 0) ? 1.f : 0.f;
    }
}

// ---------------------------------------------------------------------------
// OpenBLAS-mimic sgemm: 128x64 tile, 8x4 micro (R9 champion). kc=384 panel
// split preserved bitwise. grid (64,12). Unchanged.
// ---------------------------------------------------------------------------
__global__ __launch_bounds__(256) void gemmseq(
    const float* __restrict__ A, const float* __restrict__ W,
    const float* __restrict__ R, float* __restrict__ C)
{
    __shared__ float sA[64][132];  // [k][m], transposed, 128 m + 4 pad
    __shared__ float sB[64][68];   // [k][n]

    const int t = threadIdx.x;
    const int mbase = blockIdx.x * 128;
    const int nbase = blockIdx.y * 64;
    const int m0 = (t >> 4) * 8;
    const int n0 = (t & 15) * 4;

    float acc[8][4], accA[8][4];
#pragma unroll
    for (int i = 0; i < 8; i++)
#pragma unroll
        for (int j = 0; j < 4; j++) { acc[i][j] = 0.f; accA[i][j] = 0.f; }

    for (int k0 = 0; k0 < 768; k0 += 64) {
        __syncthreads();
#pragma unroll
        for (int i = 0; i < 8; i++) {           // A tile: 128 rows x 64 k
            const int idx = t + i * 256;        // 0..2047
            const int ar = idx >> 4;            // 0..127
            const int ak4 = (idx & 15) * 4;     // 0..60
            const float4 a4 = *(const float4*)&A[(size_t)(mbase + ar) * 768 + k0 + ak4];
            sA[ak4 + 0][ar] = a4.x;
            sA[ak4 + 1][ar] = a4.y;
            sA[ak4 + 2][ar] = a4.z;
            sA[ak4 + 3][ar] = a4.w;
        }
#pragma unroll
        for (int i = 0; i < 4; i++) {           // B tile: 64 rows x 64 n
            const int idx = t + i * 256;        // 0..1023
            const int br = idx >> 4;            // 0..63
            const int bk4 = (idx & 15) * 4;     // 0..60
            *(float4*)&sB[br][bk4] =
                *(const float4*)&W[(size_t)(k0 + br) * 768 + nbase + bk4];
        }
        __syncthreads();

        for (int kk = 0; kk < 64; kk++) {
            float av[8], bv[4];
            *(float4*)&av[0] = *(const float4*)&sA[kk][m0];
            *(float4*)&av[4] = *(const float4*)&sA[kk][m0 + 4];
            *(float4*)&bv[0] = *(const float4*)&sB[kk][n0];
#pragma unroll
            for (int i = 0; i < 8; i++)
#pragma unroll
                for (int j = 0; j < 4; j++)
                    acc[i][j] = fmaf(av[i], bv[j], acc[i][j]);
        }

        if (k0 + 64 == 384) {   // end of first kc panel (OpenBLAS kc=384)
#pragma unroll
            for (int i = 0; i < 8; i++)
#pragma unroll
                for (int j = 0; j < 4; j++) {
                    accA[i][j] = acc[i][j];
                    acc[i][j] = 0.f;
                }
        }
    }

#pragma unroll
    for (int i = 0; i < 8; i++)
#pragma unroll
        for (int j = 0; j < 4; j++) {
            const size_t idx = (size_t)(mbase + m0 + i) * 768 + nbase + n0 + j;
            float o = __fadd_rn(accA[i][j], acc[i][j]);  // C = panel0 + panel1
            if (R) o = __fadd_rn(o, R[idx]);             // np: out = tmp + x
            C[idx] = o;
        }
}

// ---------------------------------------------------------------------------
// Denominator: one THREAD per row (champion structure, wave-uniform K SMEM
// batches, XCD swizzle). q now held as NATIVE float4 qf[16] (no pointer
// casts, constant indices after unroll -> SROA-promotable), K row staged
// into kf[16] the same way; launch_bounds(128,2) raises the VGPR cap to 256
// (occupancy is grid-pinned at 1.5 waves/SIMD, so the cap is free).
// Arithmetic chain identical to R9 champion — bitwise.
// ---------------------------------------------------------------------------
__global__ __launch_bounds__(128, 2) void denom_np(
    const float* __restrict__ Q, const float* __restrict__ K,
    const float* __restrict__ MF, float* __restrict__ D)
{
    const int bid = blockIdx.x;
    const int lb  = (bid & 7) * 96 + (bid >> 3);     // XCD-grouped logical id
    const int gid = lb * 128 + threadIdx.x;          // 0..98303
    const int bh = gid >> 10;                        // uniform per block
    const int row = gid & 1023;
    const int b = bh / NH, h = bh % NH;
    const int bh_u = __builtin_amdgcn_readfirstlane(bh);
    const int b_u = bh_u / NH, h_u = bh_u % NH;

    const float mq = MF[b * NT + row];

    float4 qf[16];
    const float4* qp = (const float4*)&Q[((size_t)(b * NT + row)) * ND + h * 64];
#pragma unroll
    for (int i = 0; i < 16; i++) qf[i] = qp[i];

    const float* Kb = &K[((size_t)(b_u * NT)) * ND + h_u * 64];
    const float* MFb = &MF[b_u * NT];

    float Bi[8];
    for (int c = 0; c < 8; c++) {
        float b8[8];
        for (int s = 0; s < 128; s++) {
            const int sg = c * 128 + s;
            const float4* kp = (const float4*)(Kb + (size_t)sg * ND);  // uniform
            float4 kf[16];
#pragma unroll
            for (int i = 0; i < 16; i++) kf[i] = kp[i];
            const float dt = dot64_f4(qf, kf);
            float sc = __fmul_rn(dt, SCALE32);
            sc = __fmul_rn(sc, MFb[sg]);
            sc = __fmul_rn(sc, mq);
            const int j = s & 7;
            if (s < 8) b8[j] = sc;
            else       b8[j] = __fadd_rn(b8[j], sc);
        }
        Bi[c] = __fadd_rn(__fadd_rn(__fadd_rn(b8[0], b8[1]), __fadd_rn(b8[2], b8[3])),
                          __fadd_rn(__fadd_rn(b8[4], b8[5]), __fadd_rn(b8[6], b8[7])));
    }

    D[(size_t)bh * NT + row] = __fadd_rn(
        __fadd_rn(__fadd_rn(Bi[0], Bi[1]), __fadd_rn(Bi[2], Bi[3])),
        __fadd_rn(__fadd_rn(Bi[4], Bi[5]), __fadd_rn(Bi[6], Bi[7])));
}

// ---------------------------------------------------------------------------
// Attention out: one THREAD per row (champion structure, wave-uniform K/V
// SMEM batches, XCD swizzle). q = native float4 qf[16] (SROA-promotable,
// no casts), K row = kf[16], V row = vf[16] — all constant-indexed after
// unroll. o[64] unchanged (always register-resident). launch_bounds(128,2):
// VGPR cap 256 for qf+o+stream regs. o[j] chains over s ascending with
// per-op rounding identical to R9 champion — bitwise. Self-aliased QA.
// grid 768 x 128.
// ---------------------------------------------------------------------------
__global__ __launch_bounds__(128, 2) void attn_np(
    const float* __restrict__ K, const float* __restrict__ V,
    const float* __restrict__ D, const float* __restrict__ MF,
    float* __restrict__ QA)   // in: Q, out: A (self-aliased per row)
{
    const int bid = blockIdx.x;
    const int lb  = (bid & 7) * 96 + (bid >> 3);     // XCD-grouped logical id
    const int gid = lb * 128 + threadIdx.x;
    const int bh = gid >> 10;
    const int row = gid & 1023;
    const int b = bh / NH, h = bh % NH;
    const int bh_u = __builtin_amdgcn_readfirstlane(bh);
    const int b_u = bh_u / NH, h_u = bh_u % NH;

    const float mq = MF[b * NT + row];
    const float De = __fadd_rn(D[(size_t)bh * NT + row], EPS32);  // np: sum+eps

    float4 qf[16];
    const float4* qp = (const float4*)&QA[((size_t)(b * NT + row)) * ND + h * 64];
#pragma unroll
    for (int i = 0; i < 16; i++) qf[i] = qp[i];

    float o[64];
#pragma unroll
    for (int j = 0; j < 64; j++) o[j] = 0.f;

    const float* Kb = &K[((size_t)(b_u * NT)) * ND + h_u * 64];
    const float* Vb = &V[((size_t)(b_u * NT)) * ND + h_u * 64];
    const float* MFb = &MF[b_u * NT];

    for (int s = 0; s < NT; s++) {
        const float4* kp = (const float4*)(Kb + (size_t)s * ND);   // uniform
        float4 kf[16];
#pragma unroll
        for (int i = 0; i < 16; i++) kf[i] = kp[i];
        const float dt = dot64_f4(qf, kf);
        float sc = __fmul_rn(dt, SCALE32);
        sc = __fmul_rn(sc, MFb[s]);
        sc = __fmul_rn(sc, mq);
        const float p = __fdiv_rn(sc, De);
        const float4* vp = (const float4*)(Vb + (size_t)s * ND);   // uniform
        float4 vf[16];
#pragma unroll
        for (int i = 0; i < 16; i++) vf[i] = vp[i];
#pragma unroll
        for (int i = 0; i < 16; i++) {                // j = 4i..4i+3 ascending
            o[4*i+0] = __fadd_rn(o[4*i+0], __fmul_rn(p, vf[i].x));
            o[4*i+1] = __fadd_rn(o[4*i+1], __fmul_rn(p, vf[i].y));
            o[4*i+2] = __fadd_rn(o[4*i+2], __fmul_rn(p, vf[i].z));
            o[4*i+3] = __fadd_rn(o[4*i+3], __fmul_rn(p, vf[i].w));
        }
    }

    float4* op = (float4*)&QA[((size_t)(b * NT + row)) * ND + h * 64];
#pragma unroll
    for (int i = 0; i < 16; i++) op[i] = *(float4*)&o[i * 4];
}

// ---------------------------------------------------------------------------
// Row norm, numpy-faithful pairwise mean via ONE WAVE per row (unchanged).
// ---------------------------------------------------------------------------
__global__ __launch_bounds__(256) void rownorm_np(
    float* __restrict__ Y, const float* __restrict__ gamma,
    const float* __restrict__ beta)
{
    const int wave = threadIdx.x >> 6, lane = threadIdx.x & 63;
    const int row = blockIdx.x * 4 + wave;
    float* yr = Y + (size_t)row * ND;
    const int c = lane >> 3, j = lane & 7;

    const float* a = yr + c * 96;
    float r = a[j];
#pragma unroll
    for (int i = 1; i < 12; i++) r = __fadd_rn(r, a[i * 8 + j]);

    r = __fadd_rn(r, __shfl_xor(r, 1, 64));
    r = __fadd_rn(r, __shfl_xor(r, 2, 64));
    r = __fadd_rn(r, __shfl_xor(r, 4, 64));
    r = __fadd_rn(r, __shfl_xor(r, 8, 64));
    r = __fadd_rn(r, __shfl_xor(r, 16, 64));
    r = __fadd_rn(r, __shfl_xor(r, 32, 64));

    const float m = __fdiv_rn(r, 768.0f);
    const float mpe = __fadd_rn(m, EPS32);

#pragma unroll
    for (int i = 0; i < 12; i++) {
        const int idx = i * 64 + lane;
        const float v = yr[idx];
        float o = __fsub_rn(v, m);
        o = __fmul_rn(gamma[idx], o);
        o = __fdiv_rn(o, mpe);
        o = __fadd_rn(o, beta[idx]);
        yr[idx] = o;
    }
}

// ---------------------------------------------------------------------------
extern "C" void kernel_launch(void* const* d_in, const int* in_sizes, int n_in,
                              void* d_out, int out_size, void* d_ws, size_t ws_size,
                              hipStream_t stream)
{
    (void)in_sizes; (void)n_in; (void)out_size; (void)ws_size;
    const float* x     = (const float*)d_in[0];
    const unsigned char* maskb = (const unsigned char*)d_in[1];
    const float* wq    = (const float*)d_in[2];
    const float* wk    = (const float*)d_in[3];
    const float* wv    = (const float*)d_in[4];
    const float* wf    = (const float*)d_in[5];
    const float* gamma = (const float*)d_in[6];
    const float* beta  = (const float*)d_in[7];

    float* ws = (float*)d_ws;
    float* MF = ws;                             // 8192
    float* D  = MF + BT;                        // 96*1024
    float* Q  = D + (size_t)96 * NT;            // 8192*768 (becomes A)
    float* K  = Q + (size_t)BT * ND;            // 8192*768
    float* V  = K + (size_t)BT * ND;            // 8192*768
    float* Y  = (float*)d_out;                  // total ws: 75.9 MB

    mask_k<<<1, 256, 0, stream>>>(maskb, MF);
    gemmseq<<<dim3(64, 12), 256, 0, stream>>>(x, wq, nullptr, Q);
    gemmseq<<<dim3(64, 12), 256, 0, stream>>>(x, wk, nullptr, K);
    gemmseq<<<dim3(64, 12), 256, 0, stream>>>(x, wv, nullptr, V);
    denom_np<<<768, 128, 0, stream>>>(Q, K, MF, D);
    attn_np<<<768, 128, 0, stream>>>(K, V, D, MF, Q);  // Q -> A
    gemmseq<<<dim3(64, 12), 256, 0, stream>>>(Q, wf, x, Y);
    rownorm_np<<<2048, 256, 0, stream>>>(Y, gamma, beta);
}

// Round 15
// 1707.062 us; speedup vs baseline: 2.9150x; 1.0191x over previous
//
#include <hip/hip_runtime.h>

// Problem constants
#define NB 8
#define NT 1024
#define ND 768     // = 12*64
#define NH 12
#define NU 64
#define BT (NB*NT)   // 8192
#define SCALE32 ((float)0.03608439182435161)  // fp32(768^-0.5)
#define EPS32 1e-7f

// ---------------------------------------------------------------------------
// numpy baseline-SIMD (SSE2, no FMA) einsum dot over 64 contiguous elements:
// 4 accumulators stride-4, separate mul/add (rounded each), reduce
// (r0+r2)+(r1+r3). __f*_rn blocks hipcc contraction. BITWISE-IDENTICAL.
// ---------------------------------------------------------------------------
__device__ __forceinline__ float dot64_np(const float* a, const float* b)
{
    float r[4];
#pragma unroll
    for (int j = 0; j < 4; j++) r[j] = __fmul_rn(a[j], b[j]);
#pragma unroll
    for (int i = 1; i < 16; i++)
#pragma unroll
        for (int j = 0; j < 4; j++)
            r[j] = __fadd_rn(r[j], __fmul_rn(a[i * 4 + j], b[i * 4 + j]));
    return __fadd_rn(__fadd_rn(r[0], r[2]), __fadd_rn(r[1], r[3]));
}

// ---------------------------------------------------------------------------
// Mask decode with byte/int32 layout sniff (mask is all-ones in practice).
// ---------------------------------------------------------------------------
__global__ __launch_bounds__(256) void mask_k(
    const unsigned char* __restrict__ mb, float* __restrict__ mf)
{
    __shared__ int cntOff, cntAll;
    if (threadIdx.x == 0) { cntOff = 0; cntAll = 0; }
    __syncthreads();
    int lo = 0, la = 0;
    for (int i = threadIdx.x; i < BT; i += 256)
        if (mb[i] != 0) { la++; if ((i & 3) != 0) lo++; }
    atomicAdd(&cntOff, lo);
    atomicAdd(&cntAll, la);
    __syncthreads();
    const bool int32mode = (cntOff == 0) && (cntAll != 0);
    if (int32mode) {
        const int* mi = (const int*)mb;
        for (int i = threadIdx.x; i < BT; i += 256)
            mf[i] = (mi[i] != 0) ? 1.f : 0.f;
    } else {
        for (int i = threadIdx.x; i < BT; i += 256)
            mf[i] = (mb[i] != 0) ? 1.f : 0.f;
    }
}

// ---------------------------------------------------------------------------
// OpenBLAS-mimic sgemm, DOUBLE-BUFFERED: C = A[8192x768] @ W[768x768]
// (+R elementwise). BK=32, 24 k-tiles; sA/sB 2-deep (50 KB, 3 blocks/CU
// preserved). Per tile: prefetch kt+1 into 6 float4 regs (VMEM latency
// hides under the 32x32-FMA compute), compute from buf[cur], write regs to
// buf[cur^1] AFTER compute, ONE barrier per tile. Safety: buf[cur^1]'s last
// readers finished in iteration kt-1 (separated by that iteration's
// barrier); writes complete before kt+1's reads (this iteration's barrier).
// Per-output chain: fmaf over k ascending 0..767 with acc reset after tile
// 11 (= k 384, the OpenBLAS kc split) — BITWISE-IDENTICAL to the 8x4
// single-buffer version; only LDS transport changed. grid (64,12).
// ---------------------------------------------------------------------------
__global__ __launch_bounds__(256) void gemmseq(
    const float* __restrict__ A, const float* __restrict__ W,
    const float* __restrict__ R, float* __restrict__ C)
{
    __shared__ float sA[2][32][132];  // [buf][k][m], transposed, pad 132
    __shared__ float sB[2][32][68];   // [buf][k][n], pad 68

    const int t = threadIdx.x;
    const int mbase = blockIdx.x * 128;
    const int nbase = blockIdx.y * 64;
    const int m0 = (t >> 4) * 8;
    const int n0 = (t & 15) * 4;

    // staging coordinates (fixed per thread)
    // A tile: 128 rows x 32 k = 1024 float4 along k; idx = t + i*256
    //   mr = idx>>3 (0..127), k4 = (idx&7)*4 (0..28)
    // B tile: 32 rows x 64 n = 512 float4 along n; idx = t + i*256 (i<2)
    //   br = idx>>4 (0..31), bn4 = (idx&15)*4 (0..60)

    float acc[8][4], accA[8][4];
#pragma unroll
    for (int i = 0; i < 8; i++)
#pragma unroll
        for (int j = 0; j < 4; j++) { acc[i][j] = 0.f; accA[i][j] = 0.f; }

    // ---- prologue: stage tile 0 into buffer 0 ----
#pragma unroll
    for (int i = 0; i < 4; i++) {
        const int idx = t + i * 256;
        const int mr = idx >> 3;
        const int k4 = (idx & 7) * 4;
        const float4 a4 = *(const float4*)&A[(size_t)(mbase + mr) * 768 + k4];
        sA[0][k4 + 0][mr] = a4.x;
        sA[0][k4 + 1][mr] = a4.y;
        sA[0][k4 + 2][mr] = a4.z;
        sA[0][k4 + 3][mr] = a4.w;
    }
#pragma unroll
    for (int i = 0; i < 2; i++) {
        const int idx = t + i * 256;
        const int br = idx >> 4;
        const int bn4 = (idx & 15) * 4;
        *(float4*)&sB[0][br][bn4] =
            *(const float4*)&W[(size_t)br * 768 + nbase + bn4];
    }
    __syncthreads();

    for (int kt = 0; kt < 24; kt++) {
        const int cur = kt & 1;

        // prefetch next tile into registers (VMEM, overlaps compute below)
        float4 ra[4], rb[2];
        if (kt + 1 < 24) {
            const int k0n = (kt + 1) * 32;
#pragma unroll
            for (int i = 0; i < 4; i++) {
                const int idx = t + i * 256;
                const int mr = idx >> 3;
                const int k4 = (idx & 7) * 4;
                ra[i] = *(const float4*)&A[(size_t)(mbase + mr) * 768 + k0n + k4];
            }
#pragma unroll
            for (int i = 0; i < 2; i++) {
                const int idx = t + i * 256;
                const int br = idx >> 4;
                const int bn4 = (idx & 15) * 4;
                rb[i] = *(const float4*)&W[(size_t)(k0n + br) * 768 + nbase + bn4];
            }
        }

        // compute current tile (k ascending within tile)
        for (int kk = 0; kk < 32; kk++) {
            float av[8], bv[4];
            *(float4*)&av[0] = *(const float4*)&sA[cur][kk][m0];
            *(float4*)&av[4] = *(const float4*)&sA[cur][kk][m0 + 4];
            *(float4*)&bv[0] = *(const float4*)&sB[cur][kk][n0];
#pragma unroll
            for (int i = 0; i < 8; i++)
#pragma unroll
                for (int j = 0; j < 4; j++)
                    acc[i][j] = fmaf(av[i], bv[j], acc[i][j]);
        }

        if (kt == 11) {   // end of first kc panel (k = 384, OpenBLAS kc=384)
#pragma unroll
            for (int i = 0; i < 8; i++)
#pragma unroll
                for (int j = 0; j < 4; j++) {
                    accA[i][j] = acc[i][j];
                    acc[i][j] = 0.f;
                }
        }

        // write prefetched tile into the other buffer, then one barrier
        if (kt + 1 < 24) {
#pragma unroll
            for (int i = 0; i < 4; i++) {
                const int idx = t + i * 256;
                const int mr = idx >> 3;
                const int k4 = (idx & 7) * 4;
                sA[cur ^ 1][k4 + 0][mr] = ra[i].x;
                sA[cur ^ 1][k4 + 1][mr] = ra[i].y;
                sA[cur ^ 1][k4 + 2][mr] = ra[i].z;
                sA[cur ^ 1][k4 + 3][mr] = ra[i].w;
            }
#pragma unroll
            for (int i = 0; i < 2; i++) {
                const int idx = t + i * 256;
                const int br = idx >> 4;
                const int bn4 = (idx & 15) * 4;
                *(float4*)&sB[cur ^ 1][br][bn4] = rb[i];
            }
            __syncthreads();
        }
    }

#pragma unroll
    for (int i = 0; i < 8; i++)
#pragma unroll
        for (int j = 0; j < 4; j++) {
            const size_t idx = (size_t)(mbase + m0 + i) * 768 + nbase + n0 + j;
            float o = __fadd_rn(accA[i][j], acc[i][j]);  // C = panel0 + panel1
            if (R) o = __fadd_rn(o, R[idx]);             // np: out = tmp + x
            C[idx] = o;
        }
}

// ---------------------------------------------------------------------------
// Denominator (champion, R9 verbatim): one THREAD per row, wave-uniform K
// SMEM batches, numpy pairwise trees. grid 768 x 128, XCD-swizzled.
// ---------------------------------------------------------------------------
__global__ __launch_bounds__(128) void denom_np(
    const float* __restrict__ Q, const float* __restrict__ K,
    const float* __restrict__ MF, float* __restrict__ D)
{
    const int bid = blockIdx.x;
    const int lb  = (bid & 7) * 96 + (bid >> 3);
    const int gid = lb * 128 + threadIdx.x;
    const int bh = gid >> 10;
    const int row = gid & 1023;
    const int b = bh / NH, h = bh % NH;
    const int bh_u = __builtin_amdgcn_readfirstlane(bh);
    const int b_u = bh_u / NH, h_u = bh_u % NH;

    const float mq = MF[b * NT + row];

    float qr[64];
    const float4* qp = (const float4*)&Q[((size_t)(b * NT + row)) * ND + h * 64];
#pragma unroll
    for (int i = 0; i < 16; i++) *(float4*)&qr[i * 4] = qp[i];

    const float* Kb = &K[((size_t)(b_u * NT)) * ND + h_u * 64];
    const float* MFb = &MF[b_u * NT];

    float Bi[8];
    for (int c = 0; c < 8; c++) {
        float b8[8];
        for (int s = 0; s < 128; s++) {
            const int sg = c * 128 + s;
            const float dt = dot64_np(qr, Kb + (size_t)sg * ND);
            float sc = __fmul_rn(dt, SCALE32);
            sc = __fmul_rn(sc, MFb[sg]);
            sc = __fmul_rn(sc, mq);
            const int j = s & 7;
            if (s < 8) b8[j] = sc;
            else       b8[j] = __fadd_rn(b8[j], sc);
        }
        Bi[c] = __fadd_rn(__fadd_rn(__fadd_rn(b8[0], b8[1]), __fadd_rn(b8[2], b8[3])),
                          __fadd_rn(__fadd_rn(b8[4], b8[5]), __fadd_rn(b8[6], b8[7])));
    }

    D[(size_t)bh * NT + row] = __fadd_rn(
        __fadd_rn(__fadd_rn(Bi[0], Bi[1]), __fadd_rn(Bi[2], Bi[3])),
        __fadd_rn(__fadd_rn(Bi[4], Bi[5]), __fadd_rn(Bi[6], Bi[7])));
}

// ---------------------------------------------------------------------------
// Attention out (champion, R9 verbatim): one THREAD per row, wave-uniform
// K/V SMEM batches. grid 768 x 128, XCD-swizzled.
// ---------------------------------------------------------------------------
__global__ __launch_bounds__(128) void attn_np(
    const float* __restrict__ K, const float* __restrict__ V,
    const float* __restrict__ D, const float* __restrict__ MF,
    float* __restrict__ QA)   // in: Q, out: A (self-aliased per row)
{
    const int bid = blockIdx.x;
    const int lb  = (bid & 7) * 96 + (bid >> 3);
    const int gid = lb * 128 + threadIdx.x;
    const int bh = gid >> 10;
    const int row = gid & 1023;
    const int b = bh / NH, h = bh % NH;
    const int bh_u = __builtin_amdgcn_readfirstlane(bh);
    const int b_u = bh_u / NH, h_u = bh_u % NH;

    const float mq = MF[b * NT + row];
    const float De = __fadd_rn(D[(size_t)bh * NT + row], EPS32);  // np: sum+eps

    float qr[64];
    const float4* qp = (const float4*)&QA[((size_t)(b * NT + row)) * ND + h * 64];
#pragma unroll
    for (int i = 0; i < 16; i++) *(float4*)&qr[i * 4] = qp[i];

    float o[64];
#pragma unroll
    for (int j = 0; j < 64; j++) o[j] = 0.f;

    const float* Kb = &K[((size_t)(b_u * NT)) * ND + h_u * 64];
    const float* Vb = &V[((size_t)(b_u * NT)) * ND + h_u * 64];
    const float* MFb = &MF[b_u * NT];

    for (int s = 0; s < NT; s++) {
        const float dt = dot64_np(qr, Kb + (size_t)s * ND);  // uniform k
        float sc = __fmul_rn(dt, SCALE32);
        sc = __fmul_rn(sc, MFb[s]);
        sc = __fmul_rn(sc, mq);
        const float p = __fdiv_rn(sc, De);
        const float* vp = Vb + (size_t)s * ND;               // uniform v
#pragma unroll
        for (int j = 0; j < 64; j++)
            o[j] = __fadd_rn(o[j], __fmul_rn(p, vp[j]));     // np SSE2 axpy
    }

    float4* op = (float4*)&QA[((size_t)(b * NT + row)) * ND + h * 64];
#pragma unroll
    for (int i = 0; i < 16; i++) op[i] = *(float4*)&o[i * 4];
}

// ---------------------------------------------------------------------------
// Row norm, numpy-faithful pairwise mean via ONE WAVE per row (unchanged).
// ---------------------------------------------------------------------------
__global__ __launch_bounds__(256) void rownorm_np(
    float* __restrict__ Y, const float* __restrict__ gamma,
    const float* __restrict__ beta)
{
    const int wave = threadIdx.x >> 6, lane = threadIdx.x & 63;
    const int row = blockIdx.x * 4 + wave;
    float* yr = Y + (size_t)row * ND;
    const int c = lane >> 3, j = lane & 7;

    const float* a = yr + c * 96;
    float r = a[j];
#pragma unroll
    for (int i = 1; i < 12; i++) r = __fadd_rn(r, a[i * 8 + j]);

    r = __fadd_rn(r, __shfl_xor(r, 1, 64));
    r = __fadd_rn(r, __shfl_xor(r, 2, 64));
    r = __fadd_rn(r, __shfl_xor(r, 4, 64));
    r = __fadd_rn(r, __shfl_xor(r, 8, 64));
    r = __fadd_rn(r, __shfl_xor(r, 16, 64));
    r = __fadd_rn(r, __shfl_xor(r, 32, 64));

    const float m = __fdiv_rn(r, 768.0f);
    const float mpe = __fadd_rn(m, EPS32);

#pragma unroll
    for (int i = 0; i < 12; i++) {
        const int idx = i * 64 + lane;
        const float v = yr[idx];
        float o = __fsub_rn(v, m);
        o = __fmul_rn(gamma[idx], o);
        o = __fdiv_rn(o, mpe);
        o = __fadd_rn(o, beta[idx]);
        yr[idx] = o;
    }
}

// ---------------------------------------------------------------------------
extern "C" void kernel_launch(void* const* d_in, const int* in_sizes, int n_in,
                              void* d_out, int out_size, void* d_ws, size_t ws_size,
                              hipStream_t stream)
{
    (void)in_sizes; (void)n_in; (void)out_size; (void)ws_size;
    const float* x     = (const float*)d_in[0];
    const unsigned char* maskb = (const unsigned char*)d_in[1];
    const float* wq    = (const float*)d_in[2];
    const float* wk    = (const float*)d_in[3];
    const float* wv    = (const float*)d_in[4];
    const float* wf    = (const float*)d_in[5];
    const float* gamma = (const float*)d_in[6];
    const float* beta  = (const float*)d_in[7];

    float* ws = (float*)d_ws;
    float* MF = ws;                             // 8192
    float* D  = MF + BT;                        // 96*1024
    float* Q  = D + (size_t)96 * NT;            // 8192*768 (becomes A)
    float* K  = Q + (size_t)BT * ND;            // 8192*768
    float* V  = K + (size_t)BT * ND;            // 8192*768
    float* Y  = (float*)d_out;                  // total ws: 75.9 MB

    mask_k<<<1, 256, 0, stream>>>(maskb, MF);
    gemmseq<<<dim3(64, 12), 256, 0, stream>>>(x, wq, nullptr, Q);
    gemmseq<<<dim3(64, 12), 256, 0, stream>>>(x, wk, nullptr, K);
    gemmseq<<<dim3(64, 12), 256, 0, stream>>>(x, wv, nullptr, V);
    denom_np<<<768, 128, 0, stream>>>(Q, K, MF, D);
    attn_np<<<768, 128, 0, stream>>>(K, V, D, MF, Q);  // Q -> A
    gemmseq<<<dim3(64, 12), 256, 0, stream>>>(Q, wf, x, Y);
    rownorm_np<<<2048, 256, 0, stream>>>(Y, gamma, beta);
}